// Round 2
// 491.521 us; speedup vs baseline: 1.0282x; 1.0282x over previous
//
#include <hip/hip_runtime.h>

// Problem constants (match setup_inputs exactly: B=8,H=W=512,C=32,BH=BW=16,
// sh=sw=16, oh=ow=0, N_ACTIVE=4096). Blocks tile the output exactly.
#define NBLK_TOTAL 8192   // 8 * 32 * 32 output grid blocks
#define N_ACT      4096

// Native vector type: __builtin_nontemporal_* requires a real vector, not
// HIP's float4 class (HIP_vector_type) — that was Round 1's compile failure.
typedef float f4 __attribute__((ext_vector_type(4)));

// Scatter indices into inverse map: map[flat_block] = src_block or -1.
__global__ __launch_bounds__(256) void build_map_kernel(const int* __restrict__ idx,
                                                        int* __restrict__ map) {
    int t = blockIdx.x * 256 + threadIdx.x;
    if (t < N_ACT) {
        int n  = idx[3 * t + 0];
        int yb = idx[3 * t + 1];
        int xb = idx[3 * t + 2];
        map[(n << 10) | (yb << 5) | xb] = t;
    }
}

// Active blocks: grid = N_ACT, one WG per active block. Reads idx directly —
// no dependence on the inverse map, no early-exit waste. 32 KiB LDS transpose
// (C,r,c)->(r,c,C) with XOR swizzle (identical logic to the verified kernel).
__global__ __launch_bounds__(256) void scatter_active_kernel(const float* __restrict__ x,
                                                             const int* __restrict__ idx,
                                                             float* __restrict__ out) {
    int i   = blockIdx.x;                 // source block id
    int n   = idx[3 * i + 0];             // same address across WG -> broadcast
    int ybk = idx[3 * i + 1];
    int xbk = idx[3 * i + 2];
    size_t base = (size_t)(n * 512 + ybk * 16) * 16384 + (size_t)(xbk * 16) * 32;
    int t = threadIdx.x;

    __shared__ float lds[8192];           // 32 KiB, swizzled layout
    const f4* xb4 = (const f4*)(x + (size_t)i * 8192);

    // Stage: x block is (C=32, 256) row-major; lds[c*256 + (rc ^ 4*(c>>2))]
    #pragma unroll
    for (int k = 0; k < 8; ++k) {
        int j  = (k << 8) + t;            // float4 index 0..2047
        f4 v = __builtin_nontemporal_load(xb4 + j);
        int c  = j >> 6;                  // channel row (64 float4 per channel)
        int rc = (j & 63) << 2;           // float offset within channel row
        int sw = (c >> 2) << 2;           // 4*(c>>2): XOR swizzle, multiple of 4
        *(f4*)&lds[(c << 8) + (rc ^ sw)] = v;
    }
    __syncthreads();

    // Drain: out-linear order o = (r*16+col)*32 + c; float4 over 4 channels
    #pragma unroll
    for (int k = 0; k < 8; ++k) {
        int o4 = (k << 8) + t;            // output float4 index 0..2047
        int rc = o4 >> 3;                 // r*16 + col
        int cq = (o4 & 7) << 2;           // channel base (multiple of 4)
        // for c = cq+q (q<4): swizzle term 4*((cq+q)>>2) == cq
        f4 v;
        v.x = lds[((cq + 0) << 8) + (rc ^ cq)];
        v.y = lds[((cq + 1) << 8) + (rc ^ cq)];
        v.z = lds[((cq + 2) << 8) + (rc ^ cq)];
        v.w = lds[((cq + 3) << 8) + (rc ^ cq)];
        int r   = rc >> 4;
        int col = rc & 15;
        size_t off = base + (size_t)r * 16384 + (size_t)(col << 5) + cq;
        __builtin_nontemporal_store(v, (f4*)(out + off));
    }
}

// Inactive blocks: grid = NBLK_TOTAL, pure streaming copy y_base -> out.
// No LDS -> not occupancy-capped (32 waves/CU). Active blocks exit after one
// map load. Nontemporal: neither stream is ever re-read.
__global__ __launch_bounds__(256) void copy_inactive_kernel(const float* __restrict__ ybase,
                                                            const int* __restrict__ map,
                                                            float* __restrict__ out) {
    int b = blockIdx.x;
    if (map[b] >= 0) return;              // active: handled by scatter_active
    int n   = b >> 10;
    int rem = b & 1023;
    int ybk = rem >> 5;
    int xbk = rem & 31;
    size_t base = (size_t)(n * 512 + ybk * 16) * 16384 + (size_t)(xbk * 16) * 32;
    int t = threadIdx.x;

    // 16 rows x 512 contiguous floats each = 2048 float4, 8 per thread
    #pragma unroll
    for (int k = 0; k < 8; ++k) {
        int j = (k << 8) + t;             // float4 index 0..2047
        int r = j >> 7;                   // row in block
        int p = j & 127;                  // float4 within row
        size_t off = base + (size_t)r * 16384 + (size_t)(p << 2);
        f4 v = __builtin_nontemporal_load((const f4*)(ybase + off));
        __builtin_nontemporal_store(v, (f4*)(out + off));
    }
}

extern "C" void kernel_launch(void* const* d_in, const int* in_sizes, int n_in,
                              void* d_out, int out_size, void* d_ws, size_t ws_size,
                              hipStream_t stream) {
    const float* x     = (const float*)d_in[0];
    const float* ybase = (const float*)d_in[1];
    const int*   idx   = (const int*)d_in[2];
    float* out = (float*)d_out;
    int*   map = (int*)d_ws;

    // Active scatter first: it has no dependence on the map.
    scatter_active_kernel<<<N_ACT, 256, 0, stream>>>(x, idx, out);

    // 0xFF bytes == -1 as int32: marks all blocks inactive
    (void)hipMemsetAsync(map, 0xFF, NBLK_TOTAL * sizeof(int), stream);
    build_map_kernel<<<N_ACT / 256, 256, 0, stream>>>(idx, map);
    copy_inactive_kernel<<<NBLK_TOTAL, 256, 0, stream>>>(ybase, map, out);
}

// Round 3
// 487.062 us; speedup vs baseline: 1.0376x; 1.0092x over previous
//
#include <hip/hip_runtime.h>

// Problem constants (match setup_inputs exactly: B=8,H=W=512,C=32,BH=BW=16,
// sh=sw=16, oh=ow=0, N_ACTIVE=4096). Blocks tile the output exactly.
#define NBLK_TOTAL 8192   // 8 * 32 * 32 output grid blocks
#define N_ACT      4096

// Native vector type: __builtin_nontemporal_* requires a real Clang vector,
// not HIP's float4 class (HIP_vector_type).
typedef float f4 __attribute__((ext_vector_type(4)));

// Scatter indices into inverse map: map[flat_block] = src_block or -1.
__global__ __launch_bounds__(256) void build_map_kernel(const int* __restrict__ idx,
                                                        int* __restrict__ map) {
    int t = blockIdx.x * 256 + threadIdx.x;
    if (t < N_ACT) {
        int n  = idx[3 * t + 0];
        int yb = idx[3 * t + 1];
        int xb = idx[3 * t + 2];
        map[(n << 10) | (yb << 5) | xb] = t;
    }
}

// Single merged worker: grid = 12288 blocks in groups of 3 (2 copy + 1 scatter)
// so both streams are in flight simultaneously — one ramp/tail/launch-gap
// instead of two serialized kernels.
//   b = 3g+s, s in {0,1}: copy output-block cb = 2g+s (cb in [0,8192))
//   b = 3g+2:             scatter active source-block i = g (i in [0,4096))
__global__ __launch_bounds__(256) void worker_kernel(const float* __restrict__ x,
                                                     const float* __restrict__ ybase,
                                                     const int* __restrict__ idx,
                                                     const int* __restrict__ map,
                                                     float* __restrict__ out) {
    __shared__ float lds[8192];           // 32 KiB, swizzled (scatter path only)
    int b = blockIdx.x;
    int g = b / 3;
    int s = b - 3 * g;
    int t = threadIdx.x;

    if (s < 2) {
        // ---- copy path: inactive output block cb, pure streaming ----
        int cb = (g << 1) + s;
        if (map[cb] >= 0) return;         // active: handled by scatter path
        int n   = cb >> 10;
        int rem = cb & 1023;
        int ybk = rem >> 5;
        int xbk = rem & 31;
        size_t base = (size_t)(n * 512 + ybk * 16) * 16384 + (size_t)(xbk * 16) * 32;
        // 16 rows x 512 contiguous floats each = 2048 float4, 8 per thread
        #pragma unroll
        for (int k = 0; k < 8; ++k) {
            int j = (k << 8) + t;         // float4 index 0..2047
            int r = j >> 7;               // row in block
            int p = j & 127;              // float4 within row
            size_t off = base + (size_t)r * 16384 + (size_t)(p << 2);
            f4 v = __builtin_nontemporal_load((const f4*)(ybase + off));
            __builtin_nontemporal_store(v, (f4*)(out + off));
        }
        return;
    }

    // ---- scatter path: active block i, LDS transpose (C,r,c)->(r,c,C) ----
    int i   = g;
    int n   = idx[3 * i + 0];             // same address across WG -> broadcast
    int ybk = idx[3 * i + 1];
    int xbk = idx[3 * i + 2];
    size_t base = (size_t)(n * 512 + ybk * 16) * 16384 + (size_t)(xbk * 16) * 32;
    const f4* xb4 = (const f4*)(x + (size_t)i * 8192);

    // Stage: x block is (C=32, 256) row-major; lds[c*256 + (rc ^ 4*(c>>2))]
    #pragma unroll
    for (int k = 0; k < 8; ++k) {
        int j  = (k << 8) + t;            // float4 index 0..2047
        f4 v = __builtin_nontemporal_load(xb4 + j);
        int c  = j >> 6;                  // channel row (64 float4 per channel)
        int rc = (j & 63) << 2;           // float offset within channel row
        int sw = (c >> 2) << 2;           // 4*(c>>2): XOR swizzle, multiple of 4
        *(f4*)&lds[(c << 8) + (rc ^ sw)] = v;
    }
    __syncthreads();

    // Drain: out-linear order o = (r*16+col)*32 + c; float4 over 4 channels.
    // Bank check: bank = (t>>3) ^ 4*(t&7) -> exactly 2 lanes/bank (free).
    #pragma unroll
    for (int k = 0; k < 8; ++k) {
        int o4 = (k << 8) + t;            // output float4 index 0..2047
        int rc = o4 >> 3;                 // r*16 + col
        int cq = (o4 & 7) << 2;           // channel base (multiple of 4)
        // for c = cq+q (q<4): swizzle term 4*((cq+q)>>2) == cq
        f4 v;
        v.x = lds[((cq + 0) << 8) + (rc ^ cq)];
        v.y = lds[((cq + 1) << 8) + (rc ^ cq)];
        v.z = lds[((cq + 2) << 8) + (rc ^ cq)];
        v.w = lds[((cq + 3) << 8) + (rc ^ cq)];
        int r   = rc >> 4;
        int col = rc & 15;
        size_t off = base + (size_t)r * 16384 + (size_t)(col << 5) + cq;
        __builtin_nontemporal_store(v, (f4*)(out + off));
    }
}

extern "C" void kernel_launch(void* const* d_in, const int* in_sizes, int n_in,
                              void* d_out, int out_size, void* d_ws, size_t ws_size,
                              hipStream_t stream) {
    const float* x     = (const float*)d_in[0];
    const float* ybase = (const float*)d_in[1];
    const int*   idx   = (const int*)d_in[2];
    float* out = (float*)d_out;
    int*   map = (int*)d_ws;

    // 0xFF bytes == -1 as int32: marks all blocks inactive (32 KiB, ~1 us)
    (void)hipMemsetAsync(map, 0xFF, NBLK_TOTAL * sizeof(int), stream);
    build_map_kernel<<<N_ACT / 256, 256, 0, stream>>>(idx, map);
    worker_kernel<<<3 * N_ACT, 256, 0, stream>>>(x, ybase, idx, map, out);
}

// Round 4
// 486.803 us; speedup vs baseline: 1.0382x; 1.0005x over previous
//
#include <hip/hip_runtime.h>

// Problem constants (match setup_inputs exactly: B=8,H=W=512,C=32,BH=BW=16,
// sh=sw=16, oh=ow=0, N_ACTIVE=4096). Blocks tile the output exactly.
#define NBLK_TOTAL 8192   // 8 * 32 * 32 output grid blocks
#define N_ACT      4096

// Native vector type: __builtin_nontemporal_* requires a real Clang vector,
// not HIP's float4 class (HIP_vector_type).
typedef float f4 __attribute__((ext_vector_type(4)));

// Scatter indices into inverse map: map[flat_block] = src_block or -1.
__global__ __launch_bounds__(256) void build_map_kernel(const int* __restrict__ idx,
                                                        int* __restrict__ map) {
    int t = blockIdx.x * 256 + threadIdx.x;
    if (t < N_ACT) {
        int n  = idx[3 * t + 0];
        int yb = idx[3 * t + 1];
        int xb = idx[3 * t + 2];
        map[(n << 10) | (yb << 5) | xb] = t;
    }
}

// Single merged worker: grid = 12288 blocks in groups of 3 (2 copy + 1 scatter)
// so both streams are in flight simultaneously.
// LDS is 16 KiB (transpose runs in two row-halves) so occupancy is the full
// 8 WG/CU (32 waves) instead of the 5 WG/CU a 32 KiB buffer allowed — this is
// the last untested structural cap (coalescing/banks/serialization verified).
__global__ __launch_bounds__(256) void worker_kernel(const float* __restrict__ x,
                                                     const float* __restrict__ ybase,
                                                     const int* __restrict__ idx,
                                                     const int* __restrict__ map,
                                                     float* __restrict__ out) {
    __shared__ float lds[4096];           // 16 KiB, swizzled (scatter path only)
    int b = blockIdx.x;
    int g = b / 3;
    int s = b - 3 * g;
    int t = threadIdx.x;

    if (s < 2) {
        // ---- copy path: inactive output block cb, pure streaming ----
        int cb = (g << 1) + s;
        if (map[cb] >= 0) return;         // active: handled by scatter path
        int n   = cb >> 10;
        int rem = cb & 1023;
        int ybk = rem >> 5;
        int xbk = rem & 31;
        size_t base = (size_t)(n * 512 + ybk * 16) * 16384 + (size_t)(xbk * 16) * 32;
        // 16 rows x 512 contiguous floats each = 2048 float4, 8 per thread
        #pragma unroll
        for (int k = 0; k < 8; ++k) {
            int j = (k << 8) + t;         // float4 index 0..2047
            int r = j >> 7;               // row in block
            int p = j & 127;              // float4 within row
            size_t off = base + (size_t)r * 16384 + (size_t)(p << 2);
            f4 v = __builtin_nontemporal_load((const f4*)(ybase + off));
            __builtin_nontemporal_store(v, (f4*)(out + off));
        }
        return;
    }

    // ---- scatter path: active block i, LDS transpose (C,r,c)->(r,c,C) ----
    // Two halves over row-chunks rc = 128*h + rc', rc' in [0,128): rows 8h..8h+7.
    // Per half: channel c occupies lds[c*128 + (rc' ^ sw(c))], sw(c)=4*(c>>2).
    // Bank algebra identical to the verified 32 KiB kernel (channel stride
    // 128 = 0 mod 32 banks): stage = dense b128 (free), drain = 2 lanes/bank.
    int i   = g;
    int n   = idx[3 * i + 0];             // same address across WG -> broadcast
    int ybk = idx[3 * i + 1];
    int xbk = idx[3 * i + 2];
    size_t base = (size_t)(n * 512 + ybk * 16) * 16384 + (size_t)(xbk * 16) * 32;
    const f4* xb4 = (const f4*)(x + (size_t)i * 8192);

    #pragma unroll
    for (int h = 0; h < 2; ++h) {
        // Stage: 1024 f4, 4 per thread. x block is (C=32, 256) row-major;
        // this half reads f4 indices c*64 + 32h + m, m in [0,32).
        #pragma unroll
        for (int k = 0; k < 4; ++k) {
            int j = (k << 8) + t;         // 0..1023
            int c = j >> 5;               // channel
            int m = j & 31;               // f4 within half channel row
            f4 v = __builtin_nontemporal_load(xb4 + (c << 6) + (h << 5) + m);
            int rcp = m << 2;             // float offset within half row-chunk
            int sw  = (c >> 2) << 2;      // XOR swizzle, multiple of 4
            *(f4*)&lds[(c << 7) + (rcp ^ sw)] = v;
        }
        __syncthreads();
        // Drain: out-linear order; rc' = r'*16+col, cq = channel quad base.
        // for c = cq+q (q<4): sw(cq+q) == cq  (cq multiple of 4)
        #pragma unroll
        for (int k = 0; k < 4; ++k) {
            int o4  = (k << 8) + t;       // 0..1023
            int rcp = o4 >> 3;            // r'*16 + col, 0..127
            int cq  = (o4 & 7) << 2;      // channel base (multiple of 4)
            f4 v;
            v.x = lds[((cq + 0) << 7) + (rcp ^ cq)];
            v.y = lds[((cq + 1) << 7) + (rcp ^ cq)];
            v.z = lds[((cq + 2) << 7) + (rcp ^ cq)];
            v.w = lds[((cq + 3) << 7) + (rcp ^ cq)];
            int r   = (h << 3) + (rcp >> 4);
            int col = rcp & 15;
            size_t off = base + (size_t)r * 16384 + (size_t)(col << 5) + cq;
            __builtin_nontemporal_store(v, (f4*)(out + off));
        }
        if (h == 0) __syncthreads();      // LDS reused by second half
    }
}

extern "C" void kernel_launch(void* const* d_in, const int* in_sizes, int n_in,
                              void* d_out, int out_size, void* d_ws, size_t ws_size,
                              hipStream_t stream) {
    const float* x     = (const float*)d_in[0];
    const float* ybase = (const float*)d_in[1];
    const int*   idx   = (const int*)d_in[2];
    float* out = (float*)d_out;
    int*   map = (int*)d_ws;

    // 0xFF bytes == -1 as int32: marks all blocks inactive (32 KiB, ~1 us)
    (void)hipMemsetAsync(map, 0xFF, NBLK_TOTAL * sizeof(int), stream);
    build_map_kernel<<<N_ACT / 256, 256, 0, stream>>>(idx, map);
    worker_kernel<<<3 * N_ACT, 256, 0, stream>>>(x, ybase, idx, map, out);
}